// Round 2
// baseline (47.858 us; speedup 1.0000x reference)
//
#include <hip/hip_runtime.h>

#define NN   16384
#define CIN  64
#define COUT 64
#define KW   257
#define NOUT (NN - KW + 1)   // 16128
#define BM   256
#define NKCH 8

typedef __attribute__((ext_vector_type(8))) short short8;
typedef __attribute__((ext_vector_type(8))) unsigned short ushortx8;
typedef __attribute__((ext_vector_type(16))) float floatx16;
typedef unsigned short ushort_t;

__device__ __forceinline__ ushort_t f2bf(float f) {
  union { float f; unsigned u; } c; c.f = f;
  unsigned u = c.u;
  return (ushort_t)((u + 0x7FFFu + ((u >> 16) & 1u)) >> 16);
}
__device__ __forceinline__ float bf2f(ushort_t h) {
  union { unsigned u; float f; } c; c.u = ((unsigned)h) << 16;
  return c.f;
}

// async 16B/lane global->LDS copy. lds base must be wave-uniform; HW adds lane*16.
__device__ __forceinline__ void cp16(const void* g, void* l) {
  auto gp = (const __attribute__((address_space(1))) unsigned int*)(unsigned long long)(uintptr_t)g;
  auto lp = (__attribute__((address_space(3))) unsigned int*)(unsigned int)(uintptr_t)l;
  __builtin_amdgcn_global_load_lds(gp, lp, 16, 0, 0);
}

// prep: x -> bf16 pre-swizzled [16384][64]; kernel -> bf16 flipped+pre-swizzled
// wsz[t][co][ci] = kernel[256-t][co][ci] (reference's effective weight layout),
// 16B chunks XORed by (row&7).
// grid exactly 1026*256 = 262656 chunks (x: 131072, w: 131584), 16B out each.
__global__ void prep_convert(const float* __restrict__ x, const float* __restrict__ w,
                             ushort_t* __restrict__ xs, ushort_t* __restrict__ wsz) {
  const int c = blockIdx.x * blockDim.x + threadIdx.x;
  const float* src;
  ushort_t* dst;
  if (c < 131072) {
    const int row = c >> 3, ch = c & 7;
    src = x + (size_t)row * 64 + ((ch ^ (row & 7)) << 3);
    dst = xs + (size_t)row * 64 + (ch << 3);
  } else {
    const int c2 = c - 131072;
    const int t = c2 >> 9, r = (c2 >> 3) & 63, ch = c2 & 7;
    src = w + (size_t)(256 - t) * 4096 + r * 64 + ((ch ^ (r & 7)) << 3);
    dst = wsz + (size_t)t * 4096 + r * 64 + (ch << 3);
  }
  float4 v0 = *(const float4*)src;
  float4 v1 = *(const float4*)(src + 4);
  ushortx8 o;
  o[0] = f2bf(v0.x); o[1] = f2bf(v0.y); o[2] = f2bf(v0.z); o[3] = f2bf(v0.w);
  o[4] = f2bf(v1.x); o[5] = f2bf(v1.y); o[6] = f2bf(v1.z); o[7] = f2bf(v1.w);
  *(ushortx8*)dst = o;
}

// 4 waves: rh = w&1 (row half, 128 rows each), ks = w>>1 (ci-half split).
// Each wave computes a 128x64 tile via 4x2 fragments of mfma_f32_32x32x16_bf16,
// over half the ci-chunks of every tap; the two ci-halves are summed through
// an f32 LDS exchange in the epilogue.
__global__ __launch_bounds__(256, 2) void conv_gemm(
    const ushort_t* __restrict__ xs, const ushort_t* __restrict__ wsz,
    ushort_t* __restrict__ part) {
  __shared__ __align__(128) char smem[288 * 128 + 2 * 16384];  // 69632 B
  char* Alds = smem;
  char* Wlds = smem + 288 * 128;

  const int tid  = threadIdx.x;
  const int lane = tid & 63;
  const int w    = tid >> 6;
  const int l31  = lane & 31;
  const int lh2  = lane >> 5;      // 0/1
  const int rh   = w & 1;          // row half
  const int ks   = w >> 1;         // ci half

  const int mblk = blockIdx.x;            // 0..62
  const int g    = blockIdx.y;            // 0..7
  const int n0   = mblk * BM;
  const int t0   = (g * KW) / NKCH;       // multiples of 8 (0,32,...,224)
  const int t1   = ((g + 1) * KW) / NKCH;
  const int Tc   = t1 - t0;               // 32 (33 for g=7)
  const int NCf  = Tc >> 1;               // 16
  const bool odd = Tc & 1;

  // ---- prologue: async-stage A (288 rows = 36 KB) + W chunk 0 (2 t = 16 KB)
  const ushort_t* agbase = xs + (size_t)(n0 + t0) * 64;
#pragma unroll
  for (int i = 0; i < 9; ++i)
    cp16(agbase + ((w * 9 + i) << 9) + lane * 8, Alds + ((w * 9 + i) << 10));

  const ushort_t* wgbase = wsz + (size_t)t0 * 4096;
#pragma unroll
  for (int s = 0; s < 2; ++s)
#pragma unroll
    for (int i = 0; i < 2; ++i)
      cp16(wgbase + (size_t)s * 4096 + ((w * 2 + i) << 9) + lane * 8,
           Wlds + s * 8192 + (w * 2 + i) * 1024);
  __syncthreads();   // vmcnt(0) drain: A + chunk0 resident

  floatx16 acc[4][2];
#pragma unroll
  for (int m = 0; m < 4; ++m)
#pragma unroll
    for (int n = 0; n < 2; ++n)
      acc[m][n] = (floatx16)(0.f);

  // one tap, this wave's two ci-ksteps (K=16 each)
  auto compute_tap = [&](int tt, const char* Wl) {
#pragma unroll
    for (int kk2 = 0; kk2 < 2; ++kk2) {
      const int c0 = lh2 + 2 * (2 * ks + kk2);   // 16B chunk index, 0..7
      short8 a[4], b[2];
#pragma unroll
      for (int m = 0; m < 4; ++m) {
        const int row = tt + rh * 128 + m * 32 + l31;        // < 288
        a[m] = *(const short8*)(Alds + row * 128 + ((c0 ^ (row & 7)) << 4));
      }
#pragma unroll
      for (int n = 0; n < 2; ++n) {
        const int rw = n * 32 + l31;
        b[n] = *(const short8*)(Wl + rw * 128 + ((c0 ^ (rw & 7)) << 4));
      }
#pragma unroll
      for (int m = 0; m < 4; ++m)
#pragma unroll
        for (int n = 0; n < 2; ++n)
          acc[m][n] = __builtin_amdgcn_mfma_f32_32x32x16_bf16(a[m], b[n], acc[m][n], 0, 0, 0);
    }
  };

  for (int cc = 0; cc < NCf; ++cc) {
    const int buf = cc & 1;
    // stage next chunk into buf^1 (async; drains at the barrier below)
    if (cc + 1 < NCf) {
      const ushort_t* wg = wsz + (size_t)(t0 + (cc + 1) * 2) * 4096;
#pragma unroll
      for (int s = 0; s < 2; ++s)
#pragma unroll
        for (int i = 0; i < 2; ++i)
          cp16(wg + (size_t)s * 4096 + ((w * 2 + i) << 9) + lane * 8,
               Wlds + (buf ^ 1) * 16384 + s * 8192 + (w * 2 + i) * 1024);
    } else if (odd) {
      const ushort_t* wg = wsz + (size_t)(t0 + NCf * 2) * 4096;
#pragma unroll
      for (int i = 0; i < 2; ++i)
        cp16(wg + ((w * 2 + i) << 9) + lane * 8,
             Wlds + (buf ^ 1) * 16384 + (w * 2 + i) * 1024);
    }
    compute_tap(cc * 2,     Wlds + buf * 16384);
    compute_tap(cc * 2 + 1, Wlds + buf * 16384 + 8192);
    __syncthreads();
  }
  if (odd) compute_tap(Tc - 1, Wlds + (NCf & 1) * 16384);

  // ---- epilogue: combine ci-halves through f32 LDS, then coalesced store.
  // red[row 0..255][col 0..63] f32 = 64 KB (reuses smem).
  __syncthreads();                       // all LDS compute reads done
  float* red = (float*)smem;
  if (ks == 1) {
#pragma unroll
    for (int m = 0; m < 4; ++m)
#pragma unroll
      for (int n = 0; n < 2; ++n)
#pragma unroll
        for (int r = 0; r < 16; ++r) {
          const int row = rh * 128 + m * 32 + (r & 3) + 8 * (r >> 2) + 4 * lh2;
          red[row * 64 + n * 32 + l31] = acc[m][n][r];
        }
  }
  __syncthreads();
  if (ks == 0) {
#pragma unroll
    for (int m = 0; m < 4; ++m)
#pragma unroll
      for (int n = 0; n < 2; ++n)
#pragma unroll
        for (int r = 0; r < 16; ++r) {
          const int row = rh * 128 + m * 32 + (r & 3) + 8 * (r >> 2) + 4 * lh2;
          const int idx = row * 64 + n * 32 + l31;
          red[idx] += acc[m][n][r];
        }
  }
  __syncthreads();
  // coalesced bf16 store: 16B/lane, 8 iters cover 256x64
  ushort_t* pg = part + (size_t)g * (NOUT * 64) + (size_t)n0 * 64;
#pragma unroll
  for (int s = 0; s < 8; ++s) {
    const int e = (tid + s * 256) * 8;   // bf16 element index < 16384
    float4 f0 = *(const float4*)(red + e);
    float4 f1 = *(const float4*)(red + e + 4);
    ushortx8 o;
    o[0] = f2bf(f0.x); o[1] = f2bf(f0.y); o[2] = f2bf(f0.z); o[3] = f2bf(f0.w);
    o[4] = f2bf(f1.x); o[5] = f2bf(f1.y); o[6] = f2bf(f1.z); o[7] = f2bf(f1.w);
    *(ushortx8*)(pg + e) = o;
  }
}

// out[n][co] = bias[co] + sum_g part[g][n][co]; one thread per 8 outputs.
__global__ void reduce_out(const ushort_t* __restrict__ part, const float* __restrict__ bias,
                           float* __restrict__ out) {
  const int i = blockIdx.x * blockDim.x + threadIdx.x;   // < NOUT*8
  if (i >= NOUT * 8) return;
  const int colbase = (i & 7) * 8;
  float s[8];
#pragma unroll
  for (int j = 0; j < 8; ++j) s[j] = bias[colbase + j];
#pragma unroll
  for (int gg = 0; gg < NKCH; ++gg) {
    ushortx8 p = *(const ushortx8*)(part + (size_t)gg * (NOUT * 64) + (size_t)i * 8);
#pragma unroll
    for (int j = 0; j < 8; ++j) s[j] += bf2f(p[j]);
  }
  float4 o0 = {s[0], s[1], s[2], s[3]};
  float4 o1 = {s[4], s[5], s[6], s[7]};
  *(float4*)(out + (size_t)i * 8) = o0;
  *(float4*)(out + (size_t)i * 8 + 4) = o1;
}

// correctness fallback if ws is too small
__global__ void naive_conv(const float* __restrict__ x, const float* __restrict__ w,
                           const float* __restrict__ bias, float* __restrict__ out) {
  const int idx = blockIdx.x * blockDim.x + threadIdx.x;
  if (idx >= NOUT * COUT) return;
  const int n = idx / COUT, co = idx % COUT;
  float s = bias[co];
  for (int t = 0; t < KW; ++t) {
    const float* xr = x + (size_t)(n + t) * CIN;
    const float* wr = w + (size_t)(KW - 1 - t) * CIN * COUT + (size_t)co * CIN;
#pragma unroll 8
    for (int ci = 0; ci < CIN; ++ci) s += xr[ci] * wr[ci];
  }
  out[idx] = s;
}

extern "C" void kernel_launch(void* const* d_in, const int* in_sizes, int n_in,
                              void* d_out, int out_size, void* d_ws, size_t ws_size,
                              hipStream_t stream) {
  const float* x    = (const float*)d_in[0];
  const float* kern = (const float*)d_in[1];
  const float* bias = (const float*)d_in[2];
  float* out = (float*)d_out;

  const size_t xs_b   = (size_t)NN * CIN * 2;          // 2 MB
  const size_t ws_b   = (size_t)KW * CIN * COUT * 2;   // 2.06 MB
  const size_t part_b = (size_t)NKCH * NOUT * COUT * 2; // 16.5 MB
  const size_t need   = xs_b + ws_b + part_b;

  if (ws_size < need) {
    naive_conv<<<(NOUT * COUT + 255) / 256, 256, 0, stream>>>(x, kern, bias, out);
    return;
  }

  ushort_t* xs   = (ushort_t*)d_ws;
  ushort_t* wsz  = xs + (size_t)NN * CIN;
  ushort_t* part = wsz + (size_t)KW * CIN * COUT;

  prep_convert<<<1026, 256, 0, stream>>>(x, kern, xs, wsz);
  conv_gemm<<<dim3(NOUT / BM, NKCH), 256, 0, stream>>>(xs, wsz, part);
  reduce_out<<<(NOUT * 8 + 255) / 256, 256, 0, stream>>>(part, bias, out);
}

// Round 3
// 47.840 us; speedup vs baseline: 1.0004x; 1.0004x over previous
//
#include <hip/hip_runtime.h>

#define NN   16384
#define NPAD 512                  // zero-filled pad rows after xs
#define CIN  64
#define COUT 64
#define KW   257
#define NOUT (NN - KW + 1)        // 16128
#define BM   512
#define NKCH 8

typedef __attribute__((ext_vector_type(8))) short short8;
typedef __attribute__((ext_vector_type(8))) unsigned short ushortx8;
typedef __attribute__((ext_vector_type(4))) float floatx4;
typedef unsigned short ushort_t;

__device__ __forceinline__ ushort_t f2bf(float f) {
  union { float f; unsigned u; } c; c.f = f;
  unsigned u = c.u;
  return (ushort_t)((u + 0x7FFFu + ((u >> 16) & 1u)) >> 16);
}
__device__ __forceinline__ float bf2f(ushort_t h) {
  union { unsigned u; float f; } c; c.u = ((unsigned)h) << 16;
  return c.f;
}

// async 16B/lane global->LDS copy. lds base must be wave-uniform; HW adds lane*16.
__device__ __forceinline__ void cp16(const void* g, void* l) {
  auto gp = (const __attribute__((address_space(1))) unsigned int*)(unsigned long long)(uintptr_t)g;
  auto lp = (__attribute__((address_space(3))) unsigned int*)(unsigned int)(uintptr_t)l;
  __builtin_amdgcn_global_load_lds(gp, lp, 16, 0, 0);
}

// prep: x -> bf16 pre-swizzled [16384][64] (+512 zero pad rows);
// kernel -> bf16 flipped+pre-swizzled: wsz[t][co][ci] = kernel[256-t][co][ci],
// 16B chunks XORed by (row&7).
// grid 1042*256 = 266752 chunks (x: 131072, w: 131584, pad: 4096), 16B out each.
__global__ void prep_convert(const float* __restrict__ x, const float* __restrict__ w,
                             ushort_t* __restrict__ xs, ushort_t* __restrict__ wsz) {
  const int c = blockIdx.x * blockDim.x + threadIdx.x;
  if (c >= 262656) {               // zero-fill pad rows NN..NN+NPAD-1
    const int cz = c - 262656;
    const int row = NN + (cz >> 3), ch = cz & 7;
    *(ushortx8*)(xs + (size_t)row * 64 + (ch << 3)) = (ushortx8)(0);
    return;
  }
  const float* src;
  ushort_t* dst;
  if (c < 131072) {
    const int row = c >> 3, ch = c & 7;
    src = x + (size_t)row * 64 + ((ch ^ (row & 7)) << 3);
    dst = xs + (size_t)row * 64 + (ch << 3);
  } else {
    const int c2 = c - 131072;
    const int t = c2 >> 9, r = (c2 >> 3) & 63, ch = c2 & 7;
    src = w + (size_t)(256 - t) * 4096 + r * 64 + ((ch ^ (r & 7)) << 3);
    dst = wsz + (size_t)t * 4096 + r * 64 + (ch << 3);
  }
  float4 v0 = *(const float4*)src;
  float4 v1 = *(const float4*)(src + 4);
  ushortx8 o;
  o[0] = f2bf(v0.x); o[1] = f2bf(v0.y); o[2] = f2bf(v0.z); o[3] = f2bf(v0.w);
  o[4] = f2bf(v1.x); o[5] = f2bf(v1.y); o[6] = f2bf(v1.z); o[7] = f2bf(v1.w);
  *(ushortx8*)dst = o;
}

// 8-wave (512-thread) block, 1 block/CU, 2 waves/SIMD — the proven 8-phase
// geometry. Each wave owns a 64x64 output tile (rows n0+w*64..+63).
// A (576 rows, 72KB) staged once; W streams through a 4-deep 8KB/tap ring.
// Per tap: 2 phases {8 ds_read_b128 -> [stage t+3] -> bar -> lgkm(0) ->
// setprio(1) 16 MFMA setprio(0) -> bar}; tap-end counted vmcnt(2).
__global__ __launch_bounds__(512, 2) void conv_gemm(
    const ushort_t* __restrict__ xs, const ushort_t* __restrict__ wsz,
    ushort_t* __restrict__ part) {
  __shared__ __align__(128) char smem[576 * 128 + 4 * 8192];  // 106496 B
  char* Alds = smem;
  char* Wlds = smem + 576 * 128;

  const int tid  = threadIdx.x;
  const int lane = tid & 63;
  const int w    = tid >> 6;       // 0..7
  const int lr   = lane & 15;
  const int lh   = lane >> 4;

  const int mblk = blockIdx.x;            // 0..31
  const int g    = blockIdx.y;            // 0..7
  const int n0   = mblk * BM;
  const int t0   = (g * KW) / NKCH;
  const int t1   = ((g + 1) * KW) / NKCH;
  const int Tc   = t1 - t0;               // 32 (33 for g=7)

  // ---- prologue: A (72 loads = 9/wave) + W taps 0..2 (1/wave each)
  const ushort_t* agbase = xs + (size_t)(n0 + t0) * 64;
#pragma unroll
  for (int i = 0; i < 9; ++i)
    cp16(agbase + ((w * 9 + i) << 9) + lane * 8, Alds + ((w * 9 + i) << 10));

  const ushort_t* wgbase = wsz + (size_t)t0 * 4096;
#pragma unroll
  for (int t = 0; t < 3; ++t)
    cp16(wgbase + (size_t)t * 4096 + (w << 9) + lane * 8,
         Wlds + t * 8192 + (w << 10));
  // need A + tap0 resident; taps 1,2 (last 2 issued) may stay in flight
  asm volatile("s_waitcnt vmcnt(2)" ::: "memory");
  __builtin_amdgcn_s_barrier();

  floatx4 acc[4][4];
#pragma unroll
  for (int m = 0; m < 4; ++m)
#pragma unroll
    for (int nb = 0; nb < 4; ++nb)
      acc[m][nb] = (floatx4){0.f, 0.f, 0.f, 0.f};

  for (int t = 0; t < Tc; ++t) {
    const char* Wt = Wlds + (t & 3) * 8192;
    // ---- phase kk=0
    {
      short8 a[4], b[4];
#pragma unroll
      for (int m = 0; m < 4; ++m) {
        const int row = t + w * 64 + m * 16 + lr;            // < 576
        a[m] = *(const short8*)(Alds + row * 128 + ((lh ^ (row & 7)) << 4));
      }
#pragma unroll
      for (int nb = 0; nb < 4; ++nb) {
        const int rw = nb * 16 + lr;
        b[nb] = *(const short8*)(Wt + rw * 128 + ((lh ^ (rw & 7)) << 4));
      }
      if (t + 3 < Tc)   // stage tap t+3 into ring slot (t+3)&3
        cp16(wsz + (size_t)(t0 + t + 3) * 4096 + (w << 9) + lane * 8,
             Wlds + ((t + 3) & 3) * 8192 + (w << 10));
      __builtin_amdgcn_s_barrier();
      asm volatile("s_waitcnt lgkmcnt(0)" ::: "memory");
      __builtin_amdgcn_sched_barrier(0);
      __builtin_amdgcn_s_setprio(1);
#pragma unroll
      for (int m = 0; m < 4; ++m)
#pragma unroll
        for (int nb = 0; nb < 4; ++nb)
          acc[m][nb] = __builtin_amdgcn_mfma_f32_16x16x32_bf16(a[m], b[nb], acc[m][nb], 0, 0, 0);
      __builtin_amdgcn_s_setprio(0);
      __builtin_amdgcn_s_barrier();
    }
    // ---- phase kk=1
    {
      short8 a[4], b[4];
#pragma unroll
      for (int m = 0; m < 4; ++m) {
        const int row = t + w * 64 + m * 16 + lr;
        a[m] = *(const short8*)(Alds + row * 128 + (((lh + 4) ^ (row & 7)) << 4));
      }
#pragma unroll
      for (int nb = 0; nb < 4; ++nb) {
        const int rw = nb * 16 + lr;
        b[nb] = *(const short8*)(Wt + rw * 128 + (((lh + 4) ^ (rw & 7)) << 4));
      }
      __builtin_amdgcn_s_barrier();
      asm volatile("s_waitcnt lgkmcnt(0)" ::: "memory");
      __builtin_amdgcn_sched_barrier(0);
      __builtin_amdgcn_s_setprio(1);
#pragma unroll
      for (int m = 0; m < 4; ++m)
#pragma unroll
        for (int nb = 0; nb < 4; ++nb)
          acc[m][nb] = __builtin_amdgcn_mfma_f32_16x16x32_bf16(a[m], b[nb], acc[m][nb], 0, 0, 0);
      __builtin_amdgcn_s_setprio(0);
      // counted wait: ensure tap t+1's loads landed; keep newer ones in flight
      if (t + 3 < Tc) {
        asm volatile("s_waitcnt vmcnt(2)" ::: "memory");
      } else if (t + 2 < Tc) {
        asm volatile("s_waitcnt vmcnt(1)" ::: "memory");
      } else if (t + 1 < Tc) {
        asm volatile("s_waitcnt vmcnt(0)" ::: "memory");
      }
      __builtin_amdgcn_s_barrier();
    }
  }

  // epilogue: D layout col=lane&15, row=(lane>>4)*4+r; bf16 partials
  ushort_t* pg = part + (size_t)g * (NOUT * 64);
#pragma unroll
  for (int m = 0; m < 4; ++m)
#pragma unroll
    for (int nb = 0; nb < 4; ++nb)
#pragma unroll
      for (int r = 0; r < 4; ++r) {
        const int row = n0 + w * 64 + m * 16 + lh * 4 + r;
        const int col = nb * 16 + lr;
        if (row < NOUT) pg[(size_t)row * 64 + col] = f2bf(acc[m][nb][r]);
      }
}

// out[n][co] = bias[co] + sum_g part[g][n][co]; one thread per 8 outputs.
__global__ void reduce_out(const ushort_t* __restrict__ part, const float* __restrict__ bias,
                           float* __restrict__ out) {
  const int i = blockIdx.x * blockDim.x + threadIdx.x;   // < NOUT*8
  if (i >= NOUT * 8) return;
  const int colbase = (i & 7) * 8;
  float s[8];
#pragma unroll
  for (int j = 0; j < 8; ++j) s[j] = bias[colbase + j];
#pragma unroll
  for (int gg = 0; gg < NKCH; ++gg) {
    ushortx8 p = *(const ushortx8*)(part + (size_t)gg * (NOUT * 64) + (size_t)i * 8);
#pragma unroll
    for (int j = 0; j < 8; ++j) s[j] += bf2f(p[j]);
  }
  float4 o0 = {s[0], s[1], s[2], s[3]};
  float4 o1 = {s[4], s[5], s[6], s[7]};
  *(float4*)(out + (size_t)i * 8) = o0;
  *(float4*)(out + (size_t)i * 8 + 4) = o1;
}

// correctness fallback if ws is too small
__global__ void naive_conv(const float* __restrict__ x, const float* __restrict__ w,
                           const float* __restrict__ bias, float* __restrict__ out) {
  const int idx = blockIdx.x * blockDim.x + threadIdx.x;
  if (idx >= NOUT * COUT) return;
  const int n = idx / COUT, co = idx % COUT;
  float s = bias[co];
  for (int t = 0; t < KW; ++t) {
    const float* xr = x + (size_t)(n + t) * CIN;
    const float* wr = w + (size_t)(KW - 1 - t) * CIN * COUT + (size_t)co * CIN;
#pragma unroll 8
    for (int ci = 0; ci < CIN; ++ci) s += xr[ci] * wr[ci];
  }
  out[idx] = s;
}

extern "C" void kernel_launch(void* const* d_in, const int* in_sizes, int n_in,
                              void* d_out, int out_size, void* d_ws, size_t ws_size,
                              hipStream_t stream) {
  const float* x    = (const float*)d_in[0];
  const float* kern = (const float*)d_in[1];
  const float* bias = (const float*)d_in[2];
  float* out = (float*)d_out;

  const size_t xs_b   = (size_t)(NN + NPAD) * CIN * 2;   // 2.16 MB
  const size_t ws_b   = (size_t)KW * CIN * COUT * 2;     // 2.06 MB
  const size_t part_b = (size_t)NKCH * NOUT * COUT * 2;  // 16.5 MB
  const size_t need   = xs_b + ws_b + part_b;

  if (ws_size < need) {
    naive_conv<<<(NOUT * COUT + 255) / 256, 256, 0, stream>>>(x, kern, bias, out);
    return;
  }

  ushort_t* xs   = (ushort_t*)d_ws;
  ushort_t* wsz  = xs + (size_t)(NN + NPAD) * CIN;
  ushort_t* part = wsz + (size_t)KW * CIN * COUT;

  prep_convert<<<1042, 256, 0, stream>>>(x, kern, xs, wsz);
  conv_gemm<<<dim3(NOUT / BM + 1, NKCH), 512, 0, stream>>>(xs, wsz, part);
  reduce_out<<<(NOUT * 8 + 255) / 256, 256, 0, stream>>>(part, bias, out);
}